// Round 3
// baseline (29.435 us; speedup 1.0000x reference)
//
#include <hip/hip_runtime.h>

// Problem constants (shapes fixed by setup_inputs).
#define NCLASSES 5
#define MS 8
#define NC 128          // channels
#define HW (256 * 256)  // H*W
#define PPT 2           // pixels per thread (float2 loads/stores: 8 B/lane sweet spot)

// Per pixel: out[m] = relu( dot(image[b,:,h,w], W[l,m,:]) + b[l,m] ), l = cluster label.
// W staged in LDS as [c][l][m]: the 8 m-values for (c,l) are two 16B-aligned float4s
// (2x ds_read_b128). Only <=5 distinct addresses per read across the wave -> broadcast-
// dominated, ~2-way worst-case bank aliasing (free per m136).
// Each thread owns 2 consecutive-w pixels -> dwordx2 image loads, int2 cluster load,
// float2 stores. c-loop is hand-pipelined 4 deep to keep >=3 loads in flight/wave.

#define STAGE(v, c)                                                          \
    do {                                                                     \
        const float4* wp0 = (const float4*)&wlds[((c) * NCLASSES + l0) * MS];\
        const float4 a0 = wp0[0], a1 = wp0[1];                               \
        const float4* wp1 = (const float4*)&wlds[((c) * NCLASSES + l1) * MS];\
        const float4 b0 = wp1[0], b1 = wp1[1];                               \
        acc0[0] = fmaf(v.x, a0.x, acc0[0]);                                  \
        acc0[1] = fmaf(v.x, a0.y, acc0[1]);                                  \
        acc0[2] = fmaf(v.x, a0.z, acc0[2]);                                  \
        acc0[3] = fmaf(v.x, a0.w, acc0[3]);                                  \
        acc0[4] = fmaf(v.x, a1.x, acc0[4]);                                  \
        acc0[5] = fmaf(v.x, a1.y, acc0[5]);                                  \
        acc0[6] = fmaf(v.x, a1.z, acc0[6]);                                  \
        acc0[7] = fmaf(v.x, a1.w, acc0[7]);                                  \
        acc1[0] = fmaf(v.y, b0.x, acc1[0]);                                  \
        acc1[1] = fmaf(v.y, b0.y, acc1[1]);                                  \
        acc1[2] = fmaf(v.y, b0.z, acc1[2]);                                  \
        acc1[3] = fmaf(v.y, b0.w, acc1[3]);                                  \
        acc1[4] = fmaf(v.y, b1.x, acc1[4]);                                  \
        acc1[5] = fmaf(v.y, b1.y, acc1[5]);                                  \
        acc1[6] = fmaf(v.y, b1.z, acc1[6]);                                  \
        acc1[7] = fmaf(v.y, b1.w, acc1[7]);                                  \
    } while (0)

__global__ __launch_bounds__(256, 2) void clusterdown_kernel(
    const float* __restrict__ image,      // (B, C, H, W)
    const int* __restrict__ clusters,     // (B, 1, H, W) int32
    const float* __restrict__ Wg,         // (NCLASSES, MS, NC)
    const float* __restrict__ bg,         // (NCLASSES, MS)
    float* __restrict__ out,              // (B, MS, H, W)
    int n_pix)
{
    __shared__ float wlds[NC * NCLASSES * MS]; // 20 KiB, [c][l][m]
    __shared__ float blds[NCLASSES * MS];

    const int tid = threadIdx.x;

    for (int i = tid; i < NCLASSES * MS * NC; i += 256) {
        int l = i / (MS * NC);
        int r = i - l * (MS * NC);
        int m = r / NC;
        int c = r - m * NC;
        wlds[(c * NCLASSES + l) * MS + m] = Wg[i];
    }
    if (tid < NCLASSES * MS) blds[tid] = bg[tid];
    __syncthreads();

    const int t = blockIdx.x * 256 + tid;
    const int base = t * PPT;
    if (base >= n_pix) return;

    const int bidx = base / HW;          // HW % PPT == 0: pair never straddles a batch
    const int hw   = base - bidx * HW;

    const int2 lab2 = *(const int2*)&clusters[base];
    const bool valid0 = (lab2.x >= 0) && (lab2.x < NCLASSES);
    const bool valid1 = (lab2.y >= 0) && (lab2.y < NCLASSES);
    const int l0 = valid0 ? lab2.x : 0;
    const int l1 = valid1 ? lab2.y : 0;

    float acc0[MS], acc1[MS];
#pragma unroll
    for (int m = 0; m < MS; ++m) {
        acc0[m] = blds[l0 * MS + m];
        acc1[m] = blds[l1 * MS + m];
    }

    const float* ip = image + (size_t)bidx * NC * HW + hw;

    // 4-deep software pipeline over c.
    float2 v0 = *(const float2*)&ip[(size_t)0 * HW];
    float2 v1 = *(const float2*)&ip[(size_t)1 * HW];
    float2 v2 = *(const float2*)&ip[(size_t)2 * HW];
    float2 v3 = *(const float2*)&ip[(size_t)3 * HW];

#pragma unroll
    for (int cc = 0; cc < NC; cc += 4) {
        STAGE(v0, cc + 0);
        if (cc + 4 < NC) v0 = *(const float2*)&ip[(size_t)(cc + 4) * HW];
        STAGE(v1, cc + 1);
        if (cc + 5 < NC) v1 = *(const float2*)&ip[(size_t)(cc + 5) * HW];
        STAGE(v2, cc + 2);
        if (cc + 6 < NC) v2 = *(const float2*)&ip[(size_t)(cc + 6) * HW];
        STAGE(v3, cc + 3);
        if (cc + 7 < NC) v3 = *(const float2*)&ip[(size_t)(cc + 7) * HW];
    }

    float* op = out + (size_t)bidx * MS * HW + hw;
#pragma unroll
    for (int m = 0; m < MS; ++m) {
        float2 r;
        r.x = valid0 ? fmaxf(acc0[m], 0.0f) : 0.0f;
        r.y = valid1 ? fmaxf(acc1[m], 0.0f) : 0.0f;
        *(float2*)&op[(size_t)m * HW] = r;
    }
}

extern "C" void kernel_launch(void* const* d_in, const int* in_sizes, int n_in,
                              void* d_out, int out_size, void* d_ws, size_t ws_size,
                              hipStream_t stream) {
    const float* image  = (const float*)d_in[0];
    const int* clusters = (const int*)d_in[1];
    const float* Wg     = (const float*)d_in[2];
    const float* bg     = (const float*)d_in[3];
    float* out          = (float*)d_out;

    const int n_pix   = in_sizes[1];          // B*H*W
    const int threads = n_pix / PPT;
    const int block   = 256;
    const int grid    = (threads + block - 1) / block;

    clusterdown_kernel<<<grid, block, 0, stream>>>(image, clusters, Wg, bg, out, n_pix);
}